// Round 5
// baseline (925.461 us; speedup 1.0000x reference)
//
#include <hip/hip_runtime.h>
#include <hip/hip_cooperative_groups.h>

namespace cg = cooperative_groups;

#define N_NODES   100000
#define D_DIM     16
#define NFILT     8
#define KOUT      (D_DIM * NFILT)   // 128
#define NNZ_CNT   1600000
#define NXCD      8
#define NBUCK     (NXCD * N_NODES)  // 800000 (xcd, row) buckets

#define GRID_SORT 1024
#define BLK_SORT  256
#define GSZ_SORT  (GRID_SORT * BLK_SORT)   // 262144 threads, co-resident (4 blocks/CU)
#define CHUNK     1024                      // offs elements scanned per block

// HW_REG_XCC_ID: id=20, offset=0, size=4  ->  simm16 = ((4-1)<<11) | (0<<6) | 20
#define XCC_ID_IMM ((3 << 11) | (0 << 6) | 20)

// w_wav[n,f] = t^(2^f) - t^(2^(f+1)),  t = exp(-eig[n]); exact repeated squaring
__global__ void wav_kernel(const float* __restrict__ eig, float* __restrict__ w_wav) {
    int n = blockIdx.x * blockDim.x + threadIdx.x;
    if (n >= N_NODES) return;
    float cur = expf(-eig[n]);
    float w[NFILT];
#pragma unroll
    for (int f = 0; f < NFILT; ++f) {
        float nx = cur * cur;
        w[f] = cur - nx;
        cur = nx;
    }
    float4* p = (float4*)(w_wav + (size_t)n * NFILT);
    p[0] = make_float4(w[0], w[1], w[2], w[3]);
    p[1] = make_float4(w[4], w[5], w[6], w[7]);
}

// Pass 1: LTxI[c, (d&7)*2 + (d>>3)] += v[e] * x[r,d]   (16 threads per edge)
// Interleaved layout so gather reads {d, d+8} as one float2.
__global__ void scatter1_kernel(const float* __restrict__ x,
                                const int* __restrict__ rows,
                                const int* __restrict__ cols,
                                const float* __restrict__ v,
                                float* __restrict__ LTxI) {
    long long idx = (long long)blockIdx.x * blockDim.x + threadIdx.x;
    if (idx >= (long long)NNZ_CNT * D_DIM) return;
    int e = (int)(idx >> 4);
    int d = (int)(idx & 15);
    int r = rows[e];
    int c = cols[e];
    float val = v[e] * x[(size_t)r * D_DIM + d];
    int slot = ((d & 7) << 1) + (d >> 3);
    atomicAdd(LTxI + (size_t)c * D_DIM + slot, val);
}

// Cooperative sort: count -> grid-wide scan -> permute, all with a consistent
// per-block XCD read from hardware. ep writes are XCD-local => no cross-XCD
// line flushing (round-3's 8x write amplification).
__global__ __launch_bounds__(BLK_SORT, 4)
void sort_kernel(const int* __restrict__ rows,
                 const int* __restrict__ cols,
                 const float* __restrict__ v,
                 int* __restrict__ offs,        // [NBUCK] zeroed on entry
                 int* __restrict__ blocksums,   // [GRID_SORT]
                 int* __restrict__ blockoffs,   // [GRID_SORT]
                 int2* __restrict__ ep) {       // [NNZ]
    cg::grid_group grid = cg::this_grid();
    int xcd = __builtin_amdgcn_s_getreg(XCC_ID_IMM) & (NXCD - 1);
    int tid = threadIdx.x;
    int bid = blockIdx.x;
    int gtid = bid * BLK_SORT + tid;

    // Phase A: histogram into (xcd, row) buckets
    for (int e = gtid; e < NNZ_CNT; e += GSZ_SORT)
        atomicAdd(&offs[xcd * N_NODES + rows[e]], 1);
    grid.sync();

    __shared__ int lds[BLK_SORT];

    // Phase B1: block-local exclusive scan of this block's 1024-elem chunk
    {
        int base = bid * CHUNK + tid * 4;
        int v0 = (base + 0 < NBUCK) ? offs[base + 0] : 0;
        int v1 = (base + 1 < NBUCK) ? offs[base + 1] : 0;
        int v2 = (base + 2 < NBUCK) ? offs[base + 2] : 0;
        int v3 = (base + 3 < NBUCK) ? offs[base + 3] : 0;
        int s = v0 + v1 + v2 + v3;
        lds[tid] = s;
        __syncthreads();
        for (int off = 1; off < BLK_SORT; off <<= 1) {
            int t = (tid >= off) ? lds[tid - off] : 0;
            __syncthreads();
            lds[tid] += t;
            __syncthreads();
        }
        int incl = lds[tid];
        int p = incl - s;
        if (base + 0 < NBUCK) offs[base + 0] = p;
        if (base + 1 < NBUCK) offs[base + 1] = p + v0;
        if (base + 2 < NBUCK) offs[base + 2] = p + v0 + v1;
        if (base + 3 < NBUCK) offs[base + 3] = p + v0 + v1 + v2;
        if (tid == BLK_SORT - 1) blocksums[bid] = incl;
    }
    grid.sync();

    // Phase B2: block 0 exclusive-scans the 1024 block sums
    if (bid == 0) {
        int base = tid * 4;
        int v0 = blocksums[base + 0];
        int v1 = blocksums[base + 1];
        int v2 = blocksums[base + 2];
        int v3 = blocksums[base + 3];
        int s = v0 + v1 + v2 + v3;
        lds[tid] = s;
        __syncthreads();
        for (int off = 1; off < BLK_SORT; off <<= 1) {
            int t = (tid >= off) ? lds[tid - off] : 0;
            __syncthreads();
            lds[tid] += t;
            __syncthreads();
        }
        int p = lds[tid] - s;
        blockoffs[base + 0] = p;
        blockoffs[base + 1] = p + v0;
        blockoffs[base + 2] = p + v0 + v1;
        blockoffs[base + 3] = p + v0 + v1 + v2;
    }
    grid.sync();

    // Phase B3: add block base -> offs[] = global exclusive start of each bucket
    {
        int base = bid * CHUNK + tid * 4;
        int bo = blockoffs[bid];
        if (base + 0 < NBUCK) offs[base + 0] += bo;
        if (base + 1 < NBUCK) offs[base + 1] += bo;
        if (base + 2 < NBUCK) offs[base + 2] += bo;
        if (base + 3 < NBUCK) offs[base + 3] += bo;
    }
    grid.sync();

    // Phase C: permute. Same thread -> same edges -> same xcd as Phase A.
    // After this, offs[b] = END of segment b (start = offs[b-1], offs[-1] = 0).
    for (int e = gtid; e < NNZ_CNT; e += GSZ_SORT) {
        int b = xcd * N_NODES + rows[e];
        int pos = atomicAdd(&offs[b], 1);
        ep[pos] = make_int2(cols[e], __float_as_int(v[e]));
    }
}

// Pass 2 gather: one wave per row; lane owns outputs (lane) and (lane+64).
// All 8 segment bounds loaded upfront for MLP; LTx read as one float2.
__global__ __launch_bounds__(256) void gather2_kernel(const int* __restrict__ offs,
                                                      const int2* __restrict__ ep,
                                                      const float* __restrict__ LTxI,
                                                      const float* __restrict__ wav,
                                                      float* __restrict__ out) {
    int wave = (int)(((long long)blockIdx.x * blockDim.x + threadIdx.x) >> 6);
    if (wave >= N_NODES) return;
    int lane = threadIdx.x & 63;
    int r = wave;
    int d0 = lane >> 3;        // 0..7
    int f  = lane & 7;         // 0..7

    int ss[NXCD], ee[NXCD];
#pragma unroll
    for (int x = 0; x < NXCD; ++x) {
        int b = x * N_NODES + r;
        ss[x] = (b == 0) ? 0 : offs[b - 1];
        ee[x] = offs[b];
    }

    float acc0 = 0.f, acc1 = 0.f;
#pragma unroll
    for (int x = 0; x < NXCD; ++x) {
        int i = ss[x], end = ee[x];
        for (; i + 2 <= end; i += 2) {
            int2 e0 = ep[i], e1 = ep[i + 1];
            float w0 = wav[e0.x * NFILT + f];
            float w1 = wav[e1.x * NFILT + f];
            float2 l0 = *(const float2*)&LTxI[e0.x * D_DIM + (d0 << 1)];
            float2 l1 = *(const float2*)&LTxI[e1.x * D_DIM + (d0 << 1)];
            float vw0 = __int_as_float(e0.y) * w0;
            float vw1 = __int_as_float(e1.y) * w1;
            acc0 = fmaf(vw0, l0.x, acc0); acc1 = fmaf(vw0, l0.y, acc1);
            acc0 = fmaf(vw1, l1.x, acc0); acc1 = fmaf(vw1, l1.y, acc1);
        }
        if (i < end) {
            int2 e = ep[i];
            float w = wav[e.x * NFILT + f];
            float2 l = *(const float2*)&LTxI[e.x * D_DIM + (d0 << 1)];
            float vw = __int_as_float(e.y) * w;
            acc0 = fmaf(vw, l.x, acc0); acc1 = fmaf(vw, l.y, acc1);
        }
    }
    out[(size_t)r * KOUT + lane]      = acc0;
    out[(size_t)r * KOUT + 64 + lane] = acc1;
}

extern "C" void kernel_launch(void* const* d_in, const int* in_sizes, int n_in,
                              void* d_out, int out_size, void* d_ws, size_t ws_size,
                              hipStream_t stream) {
    const float* x      = (const float*)d_in[0];
    const int*   L_rows = (const int*)  d_in[1];
    const int*   L_cols = (const int*)  d_in[2];
    const float* L_v    = (const float*)d_in[3];
    const float* eig    = (const float*)d_in[4];
    float* out = (float*)d_out;

    // workspace layout (~26 MB); ep offset is even -> 8-byte aligned
    float* LTxI      = (float*)d_ws;                           // [N*16]   6.4 MB
    float* wav       = LTxI + (size_t)N_NODES * D_DIM;         // [N*8]    3.2 MB
    int*   offs      = (int*)(wav + (size_t)N_NODES * NFILT);  // [NBUCK]  3.2 MB
    int*   blocksums = offs + NBUCK;                           // [1024]
    int*   blockoffs = blocksums + GRID_SORT;                  // [1024]
    int2*  ep        = (int2*)(blockoffs + GRID_SORT);         // [NNZ]    12.8 MB

    hipMemsetAsync(LTxI, 0, (size_t)N_NODES * D_DIM * sizeof(float), stream);
    hipMemsetAsync(offs, 0, (size_t)NBUCK * sizeof(int), stream);

    wav_kernel<<<(N_NODES + 255) / 256, 256, 0, stream>>>(eig, wav);

    // Pass 1 (atomic scatter into L2-resident 6.4MB LTxI)
    {
        long long total = (long long)NNZ_CNT * D_DIM;
        scatter1_kernel<<<(int)((total + 255) / 256), 256, 0, stream>>>(x, L_rows, L_cols, L_v, LTxI);
    }

    // Cooperative sort (hist + scan + permute in one launch, XCD-consistent)
    {
        const int* a0 = L_rows; const int* a1 = L_cols; const float* a2 = L_v;
        int* a3 = offs; int* a4 = blocksums; int* a5 = blockoffs; int2* a6 = ep;
        void* args[] = { &a0, &a1, &a2, &a3, &a4, &a5, &a6 };
        hipLaunchCooperativeKernel((const void*)sort_kernel, dim3(GRID_SORT), dim3(BLK_SORT),
                                   args, 0, stream);
    }

    // Pass 2 (gather, no atomics)
    {
        long long threads = (long long)N_NODES * 64;   // one wave per row
        gather2_kernel<<<(int)((threads + 255) / 256), 256, 0, stream>>>(offs, ep, LTxI, wav, out);
    }
}

// Round 6
// 313.716 us; speedup vs baseline: 2.9500x; 2.9500x over previous
//
#include <hip/hip_runtime.h>

#define N_NODES   100000
#define D_DIM     16
#define NFILT     8
#define KOUT      128
#define NNZ_CNT   1600000

#define CBITS     8
#define CROWS     256                                  // rows per coarse bucket
#define NCB       ((N_NODES + CROWS - 1) / CROWS)      // 391 buckets
#define CAP       6144                                 // record slots per bucket (mean 4096, sd ~64)
#define EPB       4096                                 // edges per binA block
#define NBLKA     ((NNZ_CNT + EPB - 1) / EPB)          // 391
#define LDSCAP    6144

// w_wav[n,f] = t^(2^f) - t^(2^(f+1)),  t = exp(-eig[n]); exact repeated squaring
__global__ void wav_kernel(const float* __restrict__ eig, float* __restrict__ w_wav) {
    int n = blockIdx.x * blockDim.x + threadIdx.x;
    if (n >= N_NODES) return;
    float cur = expf(-eig[n]);
    float w[NFILT];
#pragma unroll
    for (int f = 0; f < NFILT; ++f) {
        float nx = cur * cur;
        w[f] = cur - nx;
        cur = nx;
    }
    float4* p = (float4*)(w_wav + (size_t)n * NFILT);
    p[0] = make_float4(w[0], w[1], w[2], w[3]);
    p[1] = make_float4(w[4], w[5], w[6], w[7]);
}

// Pass 1: LTxI[c, (d&7)*2 + (d>>3)] += v[e] * x[r,d]  (interleaved so gather reads {d,d+8} as float2)
__global__ void scatter1_kernel(const float* __restrict__ x,
                                const int* __restrict__ rows,
                                const int* __restrict__ cols,
                                const float* __restrict__ v,
                                float* __restrict__ LTxI) {
    long long idx = (long long)blockIdx.x * blockDim.x + threadIdx.x;
    if (idx >= (long long)NNZ_CNT * D_DIM) return;
    int e = (int)(idx >> 4);
    int d = (int)(idx & 15);
    int r = rows[e];
    int c = cols[e];
    float val = v[e] * x[(size_t)r * D_DIM + d];
    int slot = ((d & 7) << 1) + (d >> 3);
    atomicAdd(LTxI + (size_t)c * D_DIM + slot, val);
}

// binA: block-local coarse sort (391 buckets of 256 rows). Each block sorts 4096
// edges in LDS, then appends each bucket's run to that bucket's fixed region with
// ONE cursor atomicAdd — every global write is a block-private contiguous run.
// Record: x = ((row&255)<<17) | col  (col < 2^17), y = bits of v.
__global__ __launch_bounds__(256) void binA_kernel(const int* __restrict__ rows,
                                                   const int* __restrict__ cols,
                                                   const float* __restrict__ v,
                                                   int* __restrict__ gcur,
                                                   int2* __restrict__ regA) {
    __shared__ int cnt[NCB];
    __shared__ int offb[NCB];
    __shared__ int gbase[NCB];
    __shared__ int sc[512];
    __shared__ int2 rec[EPB];
    int tid = threadIdx.x;
    int e0 = blockIdx.x * EPB;
    int nE = NNZ_CNT - e0; if (nE > EPB) nE = EPB;

    for (int i = tid; i < NCB; i += 256) cnt[i] = 0;
    __syncthreads();
    for (int i = tid; i < nE; i += 256)
        atomicAdd(&cnt[rows[e0 + i] >> CBITS], 1);
    __syncthreads();

    // exclusive scan of 391 counts (padded to 512, 2 elems/thread, read-all-then-write-all)
    int i0 = tid, i1 = tid + 256;
    sc[i0] = (i0 < NCB) ? cnt[i0] : 0;
    sc[i1] = (i1 < NCB) ? cnt[i1] : 0;
    __syncthreads();
    for (int off = 1; off < 512; off <<= 1) {
        int t0 = (i0 >= off) ? sc[i0 - off] : 0;
        int t1 = (i1 >= off) ? sc[i1 - off] : 0;
        __syncthreads();
        sc[i0] += t0; sc[i1] += t1;
        __syncthreads();
    }
    if (i0 < NCB) { int cv = cnt[i0]; int st = sc[i0] - cv; offb[i0] = st;
                    gbase[i0] = cv ? atomicAdd(&gcur[i0], cv) : 0; cnt[i0] = st; }
    if (i1 < NCB) { int cv = cnt[i1]; int st = sc[i1] - cv; offb[i1] = st;
                    gbase[i1] = cv ? atomicAdd(&gcur[i1], cv) : 0; cnt[i1] = st; }
    __syncthreads();

    // scatter into LDS, bucket-sorted
    for (int i = tid; i < nE; i += 256) {
        int r = rows[e0 + i], c = cols[e0 + i];
        float val = v[e0 + i];
        int b = r >> CBITS;
        int pos = atomicAdd(&cnt[b], 1);
        rec[pos] = make_int2(((r & (CROWS - 1)) << 17) | c, __float_as_int(val));
    }
    __syncthreads();

    // copy runs out: wave per bucket (runs are ~10 records)
    int wv = tid >> 6, lane = tid & 63;
    for (int b = wv; b < NCB; b += 4) {
        int s = offb[b];
        int n = cnt[b] - s;
        size_t dst = (size_t)b * CAP + gbase[b];
        for (int i = lane; i < n; i += 64)
            regA[dst + i] = rec[s + i];
    }
}

// binB: one block per coarse bucket. Pull records into LDS, count+scan the 256
// rows, write row-sorted records back IN PLACE (block-private window -> no
// cross-block line sharing), and emit offs2[row] = {start, end} (absolute).
__global__ __launch_bounds__(256) void binB_kernel(const int* __restrict__ gcur,
                                                   int2* __restrict__ regA,
                                                   int2* __restrict__ offs2) {
    __shared__ int2 rec[LDSCAP];
    __shared__ int cnt[CROWS];
    __shared__ int sc[CROWS];
    int tid = threadIdx.x;
    int b = blockIdx.x;
    int nb = gcur[b]; if (nb > LDSCAP) nb = LDSCAP;
    size_t base = (size_t)b * CAP;

    cnt[tid] = 0;
    __syncthreads();
    for (int i = tid; i < nb; i += 256) {
        int2 r = regA[base + i];
        rec[i] = r;
        atomicAdd(&cnt[r.x >> 17], 1);
    }
    __syncthreads();

    int cv = cnt[tid];
    sc[tid] = cv;
    __syncthreads();
    for (int off = 1; off < 256; off <<= 1) {
        int t = (tid >= off) ? sc[tid - off] : 0;
        __syncthreads();
        sc[tid] += t;
        __syncthreads();
    }
    int st = sc[tid] - cv;
    int row = b * CROWS + tid;
    if (row < N_NODES)
        offs2[row] = make_int2((int)base + st, (int)base + st + cv);
    cnt[tid] = st;   // becomes cursor
    __syncthreads();

    for (int i = tid; i < nb; i += 256) {
        int2 r = rec[i];
        int p = atomicAdd(&cnt[r.x >> 17], 1);
        regA[base + p] = make_int2(r.x & 0x1FFFF, r.y);
    }
}

// Pass 2 gather: one wave per row; lane owns outputs (lane) and (lane+64).
// Single contiguous segment per row; unroll x4 for MLP; LTxI read as float2.
__global__ __launch_bounds__(256) void gather2_kernel(const int2* __restrict__ offs2,
                                                      const int2* __restrict__ ep,
                                                      const float* __restrict__ LTxI,
                                                      const float* __restrict__ wav,
                                                      float* __restrict__ out) {
    int wave = (int)(((long long)blockIdx.x * blockDim.x + threadIdx.x) >> 6);
    if (wave >= N_NODES) return;
    int lane = threadIdx.x & 63;
    int r = wave;
    int d0 = lane >> 3;        // 0..7
    int f  = lane & 7;         // 0..7
    int2 se = offs2[r];
    int i = se.x, end = se.y;
    float acc0 = 0.f, acc1 = 0.f;
    for (; i + 4 <= end; i += 4) {
        int2 e0 = ep[i], e1 = ep[i + 1], e2 = ep[i + 2], e3 = ep[i + 3];
        float w0 = wav[e0.x * NFILT + f];
        float w1 = wav[e1.x * NFILT + f];
        float w2 = wav[e2.x * NFILT + f];
        float w3 = wav[e3.x * NFILT + f];
        float2 l0 = *(const float2*)&LTxI[e0.x * D_DIM + (d0 << 1)];
        float2 l1 = *(const float2*)&LTxI[e1.x * D_DIM + (d0 << 1)];
        float2 l2 = *(const float2*)&LTxI[e2.x * D_DIM + (d0 << 1)];
        float2 l3 = *(const float2*)&LTxI[e3.x * D_DIM + (d0 << 1)];
        float vw0 = __int_as_float(e0.y) * w0;
        float vw1 = __int_as_float(e1.y) * w1;
        float vw2 = __int_as_float(e2.y) * w2;
        float vw3 = __int_as_float(e3.y) * w3;
        acc0 = fmaf(vw0, l0.x, acc0); acc1 = fmaf(vw0, l0.y, acc1);
        acc0 = fmaf(vw1, l1.x, acc0); acc1 = fmaf(vw1, l1.y, acc1);
        acc0 = fmaf(vw2, l2.x, acc0); acc1 = fmaf(vw2, l2.y, acc1);
        acc0 = fmaf(vw3, l3.x, acc0); acc1 = fmaf(vw3, l3.y, acc1);
    }
    for (; i < end; ++i) {
        int2 e = ep[i];
        float w = wav[e.x * NFILT + f];
        float2 l = *(const float2*)&LTxI[e.x * D_DIM + (d0 << 1)];
        float vw = __int_as_float(e.y) * w;
        acc0 = fmaf(vw, l.x, acc0); acc1 = fmaf(vw, l.y, acc1);
    }
    out[(size_t)r * KOUT + lane]      = acc0;
    out[(size_t)r * KOUT + 64 + lane] = acc1;
}

extern "C" void kernel_launch(void* const* d_in, const int* in_sizes, int n_in,
                              void* d_out, int out_size, void* d_ws, size_t ws_size,
                              hipStream_t stream) {
    const float* x      = (const float*)d_in[0];
    const int*   L_rows = (const int*)  d_in[1];
    const int*   L_cols = (const int*)  d_in[2];
    const float* L_v    = (const float*)d_in[3];
    const float* eig    = (const float*)d_in[4];
    float* out = (float*)d_out;

    // workspace layout (~30 MB); all int2 arrays land on even-float offsets (8B aligned)
    float* LTxI  = (float*)d_ws;                            // [N*16]      6.4 MB
    float* wav   = LTxI + (size_t)N_NODES * D_DIM;          // [N*8]       3.2 MB
    int2*  offs2 = (int2*)(wav + (size_t)N_NODES * NFILT);  // [N]         0.8 MB
    int2*  regA  = offs2 + N_NODES;                         // [NCB*CAP]  19.2 MB
    int*   gcur  = (int*)(regA + (size_t)NCB * CAP + CAP);  // [NCB] (+CAP pad before)

    hipMemsetAsync(LTxI, 0, (size_t)N_NODES * D_DIM * sizeof(float), stream);
    hipMemsetAsync(gcur, 0, (size_t)NCB * sizeof(int), stream);

    wav_kernel<<<(N_NODES + 255) / 256, 256, 0, stream>>>(eig, wav);

    // Pass 1 (atomic scatter into L2-resident 6.4MB LTxI)
    {
        long long total = (long long)NNZ_CNT * D_DIM;
        scatter1_kernel<<<(int)((total + 255) / 256), 256, 0, stream>>>(x, L_rows, L_cols, L_v, LTxI);
    }

    // Two-level block-local sort (no cross-block partial-line writes)
    binA_kernel<<<NBLKA, 256, 0, stream>>>(L_rows, L_cols, L_v, gcur, regA);
    binB_kernel<<<NCB, 256, 0, stream>>>(gcur, regA, offs2);

    // Pass 2 (gather, no atomics)
    {
        long long threads = (long long)N_NODES * 64;   // one wave per row
        gather2_kernel<<<(int)((threads + 255) / 256), 256, 0, stream>>>(offs2, regA, LTxI, wav, out);
    }
}

// Round 8
// 278.994 us; speedup vs baseline: 3.3171x; 1.1245x over previous
//
#include <hip/hip_runtime.h>

#define N_NODES   100000
#define D_DIM     16
#define NFILT     8
#define KOUT      128
#define NNZ_CNT   1600000

#define CBITS     8
#define CROWS     256                                  // rows per coarse bucket
#define NCB       ((N_NODES + CROWS - 1) / CROWS)      // 391 buckets
#define CAP       5120                                 // record slots per bucket (mean 4092, sigma 64)
#define EPB       4096                                 // edges per binA block
#define NBLKA     ((NNZ_CNT + EPB - 1) / EPB)          // 391

// fp32 -> bf16 bits with round-to-nearest-even (same as __float2bfloat16)
__device__ __forceinline__ uint f32_to_bf16_bits(float f) {
    uint u = __float_as_uint(f);
    uint r = (u + 0x7FFFu + ((u >> 16) & 1u)) >> 16;
    return r;
}

// w_wav[n,f] = t^(2^f) - t^(2^(f+1)); fp32 compute, bf16 store (RNE)
__global__ void wav_kernel(const float* __restrict__ eig, ushort* __restrict__ wavb) {
    int n = blockIdx.x * blockDim.x + threadIdx.x;
    if (n >= N_NODES) return;
    float cur = expf(-eig[n]);
    uint pk[4];
#pragma unroll
    for (int h = 0; h < 4; ++h) {
        float nx0 = cur * cur;
        float w0 = cur - nx0;
        float nx1 = nx0 * nx0;
        float w1 = nx0 - nx1;
        cur = nx1;
        pk[h] = f32_to_bf16_bits(w0) | (f32_to_bf16_bits(w1) << 16);
    }
    *(uint4*)(wavb + (size_t)n * NFILT) = make_uint4(pk[0], pk[1], pk[2], pk[3]);
}

// Pass 1: LTxI[c, (d&7)*2 + (d>>3)] += v[e] * x[r,d]  (fp32 atomic accumulate)
__global__ void scatter1_kernel(const float* __restrict__ x,
                                const int* __restrict__ rows,
                                const int* __restrict__ cols,
                                const float* __restrict__ v,
                                float* __restrict__ LTxI) {
    long long idx = (long long)blockIdx.x * blockDim.x + threadIdx.x;
    if (idx >= (long long)NNZ_CNT * D_DIM) return;
    int e = (int)(idx >> 4);
    int d = (int)(idx & 15);
    int r = rows[e];
    int c = cols[e];
    float val = v[e] * x[(size_t)r * D_DIM + d];
    int slot = ((d & 7) << 1) + (d >> 3);
    atomicAdd(LTxI + (size_t)c * D_DIM + slot, val);
}

// pack fp32 interleaved pairs -> one u32 of 2 bf16 per pair {d, d+8}
__global__ void pack_kernel(const float* __restrict__ LTxI, uint* __restrict__ LTxP) {
    int idx = blockIdx.x * blockDim.x + threadIdx.x;
    if (idx >= N_NODES * NFILT) return;
    float2 lp = *(const float2*)(LTxI + (size_t)idx * 2);
    LTxP[idx] = f32_to_bf16_bits(lp.x) | (f32_to_bf16_bits(lp.y) << 16);
}

// binA: block-local coarse sort into 391 buckets of 256 rows; per-bucket runs
// appended with ONE cursor bump -> block-private contiguous global writes.
// Record: x = ((row&255)<<17) | col, y = bits of v.
__global__ __launch_bounds__(512) void binA_kernel(const int* __restrict__ rows,
                                                   const int* __restrict__ cols,
                                                   const float* __restrict__ v,
                                                   int* __restrict__ gcur,
                                                   int2* __restrict__ regA) {
    __shared__ int cnt[NCB];
    __shared__ int offb[NCB];
    __shared__ int gbase[NCB];
    __shared__ int sc[512];
    __shared__ int2 rec[EPB];
    int tid = threadIdx.x;
    int e0 = blockIdx.x * EPB;
    int nE = NNZ_CNT - e0; if (nE > EPB) nE = EPB;

    for (int i = tid; i < NCB; i += 512) cnt[i] = 0;
    __syncthreads();
    for (int i = tid; i < nE; i += 512)
        atomicAdd(&cnt[rows[e0 + i] >> CBITS], 1);
    __syncthreads();

    // exclusive scan of 391 counts (padded to 512, 1 elem/thread)
    sc[tid] = (tid < NCB) ? cnt[tid] : 0;
    __syncthreads();
    for (int off = 1; off < 512; off <<= 1) {
        int t = (tid >= off) ? sc[tid - off] : 0;
        __syncthreads();
        sc[tid] += t;
        __syncthreads();
    }
    if (tid < NCB) {
        int cv = cnt[tid];
        int st = sc[tid] - cv;
        offb[tid] = st;
        gbase[tid] = cv ? atomicAdd(&gcur[tid], cv) : 0;
        cnt[tid] = st;   // becomes cursor
    }
    __syncthreads();

    for (int i = tid; i < nE; i += 512) {
        int r = rows[e0 + i], c = cols[e0 + i];
        float val = v[e0 + i];
        int b = r >> CBITS;
        int pos = atomicAdd(&cnt[b], 1);
        rec[pos] = make_int2(((r & (CROWS - 1)) << 17) | c, __float_as_int(val));
    }
    __syncthreads();

    // copy runs out: wave per bucket (~10.5 records per run)
    int wv = tid >> 6, lane = tid & 63;
    for (int b = wv; b < NCB; b += 8) {
        int s = offb[b];
        int n = cnt[b] - s;
        size_t dst = (size_t)b * CAP + gbase[b];
        for (int i = lane; i < n; i += 64)
            regA[dst + i] = rec[s + i];
    }
}

// binB: one block per bucket; LDS count+scan over 256 rows; row-sorted records
// written back IN PLACE (block-private window); offs2[row] = {start, end}.
__global__ __launch_bounds__(512) void binB_kernel(const int* __restrict__ gcur,
                                                   int2* __restrict__ regA,
                                                   int2* __restrict__ offs2) {
    __shared__ int2 rec[CAP];
    __shared__ int cnt[CROWS];
    __shared__ int sc[CROWS];
    int tid = threadIdx.x;
    int b = blockIdx.x;
    int nb = gcur[b]; if (nb > CAP) nb = CAP;
    size_t base = (size_t)b * CAP;

    if (tid < CROWS) cnt[tid] = 0;
    __syncthreads();
    for (int i = tid; i < nb; i += 512) {
        int2 r = regA[base + i];
        rec[i] = r;
        atomicAdd(&cnt[r.x >> 17], 1);
    }
    __syncthreads();

    int cv = (tid < CROWS) ? cnt[tid] : 0;
    if (tid < CROWS) sc[tid] = cv;
    __syncthreads();
    for (int off = 1; off < CROWS; off <<= 1) {
        int t = (tid < CROWS && tid >= off) ? sc[tid - off] : 0;
        __syncthreads();
        if (tid < CROWS) sc[tid] += t;
        __syncthreads();
    }
    if (tid < CROWS) {
        int st = sc[tid] - cv;
        int row = b * CROWS + tid;
        if (row < N_NODES)
            offs2[row] = make_int2((int)base + st, (int)base + st + cv);
        cnt[tid] = st;   // becomes cursor
    }
    __syncthreads();

    for (int i = tid; i < nb; i += 512) {
        int2 r = rec[i];
        int p = atomicAdd(&cnt[r.x >> 17], 1);
        regA[base + p] = make_int2(r.x & 0x1FFFF, r.y);
    }
}

// Pass 2 gather: one wave per row; lane owns outputs (lane) and (lane+64).
// bf16-packed operands: LTxP u32 = {bf16 d, bf16 d+8}, wav bf16.
__global__ __launch_bounds__(256) void gather2_kernel(const int2* __restrict__ offs2,
                                                      const int2* __restrict__ ep,
                                                      const uint* __restrict__ LTxP,
                                                      const ushort* __restrict__ wavb,
                                                      float* __restrict__ out) {
    int wave = (int)(((long long)blockIdx.x * blockDim.x + threadIdx.x) >> 6);
    if (wave >= N_NODES) return;
    int lane = threadIdx.x & 63;
    int r = wave;
    int d0 = lane >> 3;        // pair index 0..7
    int f  = lane & 7;         // 0..7
    int2 se = offs2[r];
    int i = se.x, end = se.y;
    float acc0 = 0.f, acc1 = 0.f;
    for (; i + 4 <= end; i += 4) {
        int2 e0 = ep[i], e1 = ep[i + 1], e2 = ep[i + 2], e3 = ep[i + 3];
        uint l0 = LTxP[e0.x * NFILT + d0];
        uint l1 = LTxP[e1.x * NFILT + d0];
        uint l2 = LTxP[e2.x * NFILT + d0];
        uint l3 = LTxP[e3.x * NFILT + d0];
        uint w0 = wavb[e0.x * NFILT + f];
        uint w1 = wavb[e1.x * NFILT + f];
        uint w2 = wavb[e2.x * NFILT + f];
        uint w3 = wavb[e3.x * NFILT + f];
        float vw0 = __int_as_float(e0.y) * __uint_as_float(w0 << 16);
        float vw1 = __int_as_float(e1.y) * __uint_as_float(w1 << 16);
        float vw2 = __int_as_float(e2.y) * __uint_as_float(w2 << 16);
        float vw3 = __int_as_float(e3.y) * __uint_as_float(w3 << 16);
        acc0 = fmaf(vw0, __uint_as_float(l0 << 16), acc0);
        acc1 = fmaf(vw0, __uint_as_float(l0 & 0xFFFF0000u), acc1);
        acc0 = fmaf(vw1, __uint_as_float(l1 << 16), acc0);
        acc1 = fmaf(vw1, __uint_as_float(l1 & 0xFFFF0000u), acc1);
        acc0 = fmaf(vw2, __uint_as_float(l2 << 16), acc0);
        acc1 = fmaf(vw2, __uint_as_float(l2 & 0xFFFF0000u), acc1);
        acc0 = fmaf(vw3, __uint_as_float(l3 << 16), acc0);
        acc1 = fmaf(vw3, __uint_as_float(l3 & 0xFFFF0000u), acc1);
    }
    for (; i < end; ++i) {
        int2 e = ep[i];
        uint l = LTxP[e.x * NFILT + d0];
        uint w = wavb[e.x * NFILT + f];
        float vw = __int_as_float(e.y) * __uint_as_float(w << 16);
        acc0 = fmaf(vw, __uint_as_float(l << 16), acc0);
        acc1 = fmaf(vw, __uint_as_float(l & 0xFFFF0000u), acc1);
    }
    out[(size_t)r * KOUT + lane]      = acc0;
    out[(size_t)r * KOUT + 64 + lane] = acc1;
}

extern "C" void kernel_launch(void* const* d_in, const int* in_sizes, int n_in,
                              void* d_out, int out_size, void* d_ws, size_t ws_size,
                              hipStream_t stream) {
    const float* x      = (const float*)d_in[0];
    const int*   L_rows = (const int*)  d_in[1];
    const int*   L_cols = (const int*)  d_in[2];
    const float* L_v    = (const float*)d_in[3];
    const float* eig    = (const float*)d_in[4];
    float* out = (float*)d_out;

    // workspace layout (~28 MB), 8B-aligned segments
    float*  LTxI  = (float*)d_ws;                             // [N*16]     6.4 MB (fp32 accum)
    uint*   LTxP  = (uint*)(LTxI + (size_t)N_NODES * D_DIM);  // [N*8]      3.2 MB (bf16 pairs)
    ushort* wavb  = (ushort*)(LTxP + (size_t)N_NODES * NFILT);// [N*8]      1.6 MB (bf16)
    int2*   offs2 = (int2*)(wavb + (size_t)N_NODES * NFILT);  // [N]        0.8 MB
    int2*   regA  = offs2 + N_NODES;                          // [NCB*CAP] 16.0 MB
    int*    gcur  = (int*)(regA + (size_t)NCB * CAP);         // [NCB]

    hipMemsetAsync(LTxI, 0, (size_t)N_NODES * D_DIM * sizeof(float), stream);
    hipMemsetAsync(gcur, 0, (size_t)NCB * sizeof(int), stream);

    wav_kernel<<<(N_NODES + 255) / 256, 256, 0, stream>>>(eig, wavb);

    // Pass 1 (fp32 atomic scatter), then bf16 pack
    {
        long long total = (long long)NNZ_CNT * D_DIM;
        scatter1_kernel<<<(int)((total + 255) / 256), 256, 0, stream>>>(x, L_rows, L_cols, L_v, LTxI);
    }
    pack_kernel<<<(N_NODES * NFILT + 255) / 256, 256, 0, stream>>>(LTxI, LTxP);

    // Two-level block-local sort
    binA_kernel<<<NBLKA, 512, 0, stream>>>(L_rows, L_cols, L_v, gcur, regA);
    binB_kernel<<<NCB, 512, 0, stream>>>(gcur, regA, offs2);

    // Pass 2 (gather, no atomics, bf16 operands)
    {
        long long threads = (long long)N_NODES * 64;   // one wave per row
        gather2_kernel<<<(int)((threads + 255) / 256), 256, 0, stream>>>(offs2, regA, LTxP, wavb, out);
    }
}